// Round 5
// baseline (2731.599 us; speedup 1.0000x reference)
//
#include <hip/hip_runtime.h>
#include <hip/hip_bf16.h>

#define BB   128   // batch
#define TT   512   // seq len
#define II   256   // input dim
#define HH   512   // hidden dim
#define G3   1536  // 3*H

typedef __attribute__((ext_vector_type(8))) short short8;
typedef __attribute__((ext_vector_type(4))) float f32x4;
typedef __attribute__((ext_vector_type(4))) unsigned int u32x4;

__device__ __forceinline__ float bf2f(unsigned short u) {
    union { unsigned int u; float f; } p; p.u = ((unsigned int)u) << 16; return p.f;
}
__device__ __forceinline__ unsigned short f2bf(float f) {
    union { float f; unsigned int u; } p; p.f = f;
    unsigned int r = p.u + 0x7fffu + ((p.u >> 16) & 1u);  // RNE
    return (unsigned short)(r >> 16);
}
__device__ __forceinline__ float sigmoidf_fast(float x) {
    return 1.0f / (1.0f + __expf(-x));
}
__device__ __forceinline__ float tanhf_fast(float x) {
    return 1.0f - 2.0f / (1.0f + __expf(2.0f * x));
}

// coherent 16B load (bypass L1/L2 so remote agent stores are visible);
// does NOT wait — caller must s_waitcnt vmcnt(0) + sched_barrier(0).
__device__ __forceinline__ void gld16(u32x4& dst, const void* addr) {
    asm volatile("global_load_dwordx4 %0, %1, off sc0 sc1"
                 : "=v"(dst) : "v"(addr));
}

// ---------------------------------------------------------------------------
// Kernel 1: xg[t][b][g] = bf16( x[b,t,:] @ W_ih[g,:] + b_ih[g] )   (unchanged)
// ---------------------------------------------------------------------------
__global__ __launch_bounds__(256) void xgate_gemm(
    const float* __restrict__ x,       // [B,T,I]
    const float* __restrict__ Wih,     // [1536,256]
    const float* __restrict__ bih,     // [1536]
    unsigned short* __restrict__ xg)   // [T,B,1536] bf16
{
    __shared__ unsigned short AS[128][40];
    __shared__ unsigned short BS[128][40];

    const int t   = blockIdx.y;
    const int g0  = blockIdx.x * 128;
    const int tid = threadIdx.x;
    const int lane = tid & 63;
    const int w    = tid >> 6;
    const int wr   = w >> 1, wc = w & 1;

    f32x4 acc[4][4];
#pragma unroll
    for (int a = 0; a < 4; ++a)
#pragma unroll
        for (int b = 0; b < 4; ++b) acc[a][b] = (f32x4)(0.0f);

    for (int kk = 0; kk < 8; ++kk) {
        const int k0 = kk * 32;
#pragma unroll
        for (int ii = 0; ii < 4; ++ii) {
            int slot = tid + 256 * ii;
            int row  = slot >> 3;
            int c4   = slot & 7;
            float4 av = *(const float4*)(x + ((size_t)row * TT + t) * II + k0 + c4 * 4);
            unsigned short* ap = &AS[row][c4 * 4];
            ap[0] = f2bf(av.x); ap[1] = f2bf(av.y); ap[2] = f2bf(av.z); ap[3] = f2bf(av.w);
            float4 bv = *(const float4*)(Wih + (size_t)(g0 + row) * II + k0 + c4 * 4);
            unsigned short* bp = &BS[row][c4 * 4];
            bp[0] = f2bf(bv.x); bp[1] = f2bf(bv.y); bp[2] = f2bf(bv.z); bp[3] = f2bf(bv.w);
        }
        __syncthreads();

        const int kc = (lane >> 4) * 8;
        short8 a[4], b[4];
#pragma unroll
        for (int mi = 0; mi < 4; ++mi)
            a[mi] = *(const short8*)&AS[wr * 64 + mi * 16 + (lane & 15)][kc];
#pragma unroll
        for (int ni = 0; ni < 4; ++ni)
            b[ni] = *(const short8*)&BS[wc * 64 + ni * 16 + (lane & 15)][kc];
#pragma unroll
        for (int mi = 0; mi < 4; ++mi)
#pragma unroll
            for (int ni = 0; ni < 4; ++ni)
                acc[mi][ni] = __builtin_amdgcn_mfma_f32_16x16x32_bf16(a[mi], b[ni], acc[mi][ni], 0, 0, 0);
        __syncthreads();
    }

#pragma unroll
    for (int ni = 0; ni < 4; ++ni) {
        const int col = wc * 64 + ni * 16 + (lane & 15);
        const float bias = bih[g0 + col];
#pragma unroll
        for (int mi = 0; mi < 4; ++mi) {
#pragma unroll
            for (int i = 0; i < 4; ++i) {
                const int row = wr * 64 + mi * 16 + (lane >> 4) * 4 + i;
                xg[((size_t)t * BB + row) * G3 + g0 + col] = f2bf(acc[mi][ni][i] + bias);
            }
        }
    }
}

// ---------------------------------------------------------------------------
// Kernel 2 v4: single-wave blocks, direct-to-register h exchange.
// 256 blocks x 64 thr = 8 groups (16 batch rows) x 32 members (16 h-dims).
// No LDS, no barriers. Each lane polls exactly its own MFMA A-fragment words
// (16B coherent loads, tag in high dword of each 8B pair); per-ks done-mask
// so retries reload only pending fragments. W_hh slice (3x16x512) lives in
// registers (192 VGPR). Tagged parity double-buffer as in v3 (same safety
// induction: parity overwritten with t+2 only after all t+1 tags observed).
// ---------------------------------------------------------------------------
__global__ __launch_bounds__(64, 1) void gru_scan(
    const unsigned short* __restrict__ xg,    // [T,B,1536] bf16
    const float* __restrict__ Whh,            // [1536,512]
    const float* __restrict__ bhh,            // [1536]
    float* __restrict__ out,                  // [B,H]
    unsigned long long* __restrict__ hb64)    // [2][B][256] tagged pairs
{
    const int g    = blockIdx.x & 7;     // group: batch rows 16g..16g+15
    const int mm   = blockIdx.x >> 3;    // member: h dims 16mm..16mm+15
    const int lane = threadIdx.x & 63;

    // ---- W_hh slice -> registers (B-fragment order), one-time ----
    const int jj = mm * 16 + (lane & 15);           // this lane's global j
    short8 Wr[3][16];
    {
        const int kofs = (lane >> 4) * 8;
#pragma unroll
        for (int q = 0; q < 3; ++q) {
            const float* wrow = Whh + ((size_t)(q * HH + jj)) * HH + kofs;
#pragma unroll
            for (int ks = 0; ks < 16; ++ks) {
                float4 v0 = *(const float4*)(wrow + ks * 32);
                float4 v1 = *(const float4*)(wrow + ks * 32 + 4);
                union { short8 s; unsigned int u[4]; } pk;
                pk.u[0] = (unsigned int)f2bf(v0.x) | ((unsigned int)f2bf(v0.y) << 16);
                pk.u[1] = (unsigned int)f2bf(v0.z) | ((unsigned int)f2bf(v0.w) << 16);
                pk.u[2] = (unsigned int)f2bf(v1.x) | ((unsigned int)f2bf(v1.y) << 16);
                pk.u[3] = (unsigned int)f2bf(v1.z) | ((unsigned int)f2bf(v1.w) << 16);
                Wr[q][ks] = pk.s;
            }
        }
    }

    const float bhr = bhh[jj];
    const float bhz = bhh[HH + jj];
    const float bhn = bhh[2 * HH + jj];
    const int b0 = (lane >> 4) * 4;                 // first of 4 batch rows

    float hh[4] = {0.0f, 0.0f, 0.0f, 0.0f};        // carried fp32 state

    // per-lane poll base: row = lane&15, pair subgroup = (lane>>4)*4
    const char* rowb0 = (const char*)hb64 +
        (((size_t)g * 16 + (lane & 15)) * 256 + ((lane >> 4) << 2)) * 8;
    const size_t PARITY_B = (size_t)BB * 256 * 8;   // bytes per parity plane

    for (int t = 0; t < TT; ++t) {
        // ---- xg prefetch (in flight alongside first poll iteration) ----
        const unsigned short* xp = xg + ((size_t)t * BB + g * 16) * G3 + jj;
        float xr[4], xz[4], xn[4];
#pragma unroll
        for (int i = 0; i < 4; ++i) {
            const unsigned short* p = xp + (size_t)(b0 + i) * G3;
            xr[i] = bf2f(p[0]); xz[i] = bf2f(p[HH]); xn[i] = bf2f(p[2 * HH]);
        }

        // ---- poll own A-fragment words; per-ks done mask prunes retries ----
        const unsigned int want = (unsigned int)t;
        const char* pb = rowb0 + (size_t)(t & 1) * PARITY_B;
        u32x4 d2[32];
        unsigned int done = 0;
        while (true) {
#pragma unroll
            for (int ks = 0; ks < 16; ++ks) {
                if (!(done & (1u << ks))) {
                    gld16(d2[2 * ks],     pb + ks * 128);
                    gld16(d2[2 * ks + 1], pb + ks * 128 + 16);
                }
            }
            asm volatile("s_waitcnt vmcnt(0)" ::: "memory");
            __builtin_amdgcn_sched_barrier(0);
#pragma unroll
            for (int ks = 0; ks < 16; ++ks) {
                if (!(done & (1u << ks))) {
                    if (d2[2 * ks][1] == want && d2[2 * ks][3] == want &&
                        d2[2 * ks + 1][1] == want && d2[2 * ks + 1][3] == want)
                        done |= 1u << ks;
                }
            }
            if (__all(done == 0xffffu)) break;
        }

        // ---- MFMA: build A-fragment from loaded pairs, 3 gates, K=512 ----
        f32x4 aR = (f32x4)(0.0f), aZ = (f32x4)(0.0f), aN = (f32x4)(0.0f);
#pragma unroll
        for (int ks = 0; ks < 16; ++ks) {
            union { short8 s; unsigned int u[4]; } pk;
            pk.u[0] = d2[2 * ks][0];
            pk.u[1] = d2[2 * ks][2];
            pk.u[2] = d2[2 * ks + 1][0];
            pk.u[3] = d2[2 * ks + 1][2];
            aR = __builtin_amdgcn_mfma_f32_16x16x32_bf16(pk.s, Wr[0][ks], aR, 0, 0, 0);
            aZ = __builtin_amdgcn_mfma_f32_16x16x32_bf16(pk.s, Wr[1][ks], aZ, 0, 0, 0);
            aN = __builtin_amdgcn_mfma_f32_16x16x32_bf16(pk.s, Wr[2][ks], aN, 0, 0, 0);
        }

        // ---- gates in-register; tagged publish ----
        const unsigned long long tag = ((unsigned long long)(t + 1)) << 32;
        unsigned long long* dst = hb64 + (size_t)((t + 1) & 1) * BB * 256;
#pragma unroll
        for (int i = 0; i < 4; ++i) {
            float r = sigmoidf_fast(xr[i] + aR[i] + bhr);
            float z = sigmoidf_fast(xz[i] + aZ[i] + bhz);
            float n = tanhf_fast(xn[i] + r * (aN[i] + bhn));
            hh[i] = (1.0f - z) * n + z * hh[i];
            unsigned int u  = (unsigned int)f2bf(hh[i]);
            unsigned int pv = (unsigned int)__shfl_xor((int)u, 1);
            if ((lane & 1) == 0) {
                unsigned long long word = tag | (unsigned long long)(u | (pv << 16));
                __hip_atomic_store(&dst[(size_t)(g * 16 + b0 + i) * 256 + (jj >> 1)], word,
                                   __ATOMIC_RELAXED, __HIP_MEMORY_SCOPE_AGENT);
            }
            if (t == TT - 1)
                out[(size_t)(g * 16 + b0 + i) * HH + jj] = hh[i];
        }
    }
}

// ---------------------------------------------------------------------------
extern "C" void kernel_launch(void* const* d_in, const int* in_sizes, int n_in,
                              void* d_out, int out_size, void* d_ws, size_t ws_size,
                              hipStream_t stream) {
    const float* x   = (const float*)d_in[0];
    const float* Wih = (const float*)d_in[1];
    const float* Whh = (const float*)d_in[2];
    const float* bih = (const float*)d_in[3];
    const float* bhh = (const float*)d_in[4];
    float* out = (float*)d_out;

    const size_t XG_BYTES   = (size_t)TT * BB * G3 * 2;        // 192 MiB bf16
    unsigned short* xg      = (unsigned short*)d_ws;
    unsigned long long* hb64 = (unsigned long long*)((char*)d_ws + XG_BYTES);
    const size_t HBUF_BYTES = (size_t)2 * BB * 256 * 8;        // 512 KiB tagged pairs

    // tags must start at 0 (= h(0) valid, value 0)
    hipMemsetAsync((char*)d_ws + XG_BYTES, 0, HBUF_BYTES, stream);

    dim3 g1(G3 / 128, TT);
    xgate_gemm<<<g1, 256, 0, stream>>>(x, Wih, bih, xg);

    gru_scan<<<256, 64, 0, stream>>>(xg, Whh, bhh, out, hb64);
}

// Round 6
// 1820.229 us; speedup vs baseline: 1.5007x; 1.5007x over previous
//
#include <hip/hip_runtime.h>
#include <hip/hip_bf16.h>

#define BB   128   // batch
#define TT   512   // seq len
#define II   256   // input dim
#define HH   512   // hidden dim
#define G3   1536  // 3*H

typedef __attribute__((ext_vector_type(8))) short short8;
typedef __attribute__((ext_vector_type(4))) float f32x4;
typedef __attribute__((ext_vector_type(4))) unsigned int u32x4;

__device__ __forceinline__ float bf2f(unsigned short u) {
    union { unsigned int u; float f; } p; p.u = ((unsigned int)u) << 16; return p.f;
}
__device__ __forceinline__ unsigned short f2bf(float f) {
    union { float f; unsigned int u; } p; p.f = f;
    unsigned int r = p.u + 0x7fffu + ((p.u >> 16) & 1u);  // RNE
    return (unsigned short)(r >> 16);
}
__device__ __forceinline__ float sigmoidf_fast(float x) {
    return 1.0f / (1.0f + __expf(-x));
}
__device__ __forceinline__ float tanhf_fast(float x) {
    return 1.0f - 2.0f / (1.0f + __expf(2.0f * x));
}

// coherent 16B load with literal offset (bypass L1/L2: remote stores visible).
// Caller must s_waitcnt vmcnt(0) + sched_barrier(0) before using dst (rule #18).
#define GLD16O(dst, base, OFFSTR)                                         \
    asm volatile("global_load_dwordx4 %0, %1, off offset:" OFFSTR " sc0 sc1" \
                 : "=v"(dst) : "v"(base))

// ---------------------------------------------------------------------------
// Kernel 1: xg[t][b][g] = bf16( x[b,t,:] @ W_ih[g,:] + b_ih[g] )   (unchanged)
// ---------------------------------------------------------------------------
__global__ __launch_bounds__(256) void xgate_gemm(
    const float* __restrict__ x,       // [B,T,I]
    const float* __restrict__ Wih,     // [1536,256]
    const float* __restrict__ bih,     // [1536]
    unsigned short* __restrict__ xg)   // [T,B,1536] bf16
{
    __shared__ unsigned short AS[128][40];
    __shared__ unsigned short BS[128][40];

    const int t   = blockIdx.y;
    const int g0  = blockIdx.x * 128;
    const int tid = threadIdx.x;
    const int lane = tid & 63;
    const int w    = tid >> 6;
    const int wr   = w >> 1, wc = w & 1;

    f32x4 acc[4][4];
#pragma unroll
    for (int a = 0; a < 4; ++a)
#pragma unroll
        for (int b = 0; b < 4; ++b) acc[a][b] = (f32x4)(0.0f);

    for (int kk = 0; kk < 8; ++kk) {
        const int k0 = kk * 32;
#pragma unroll
        for (int ii = 0; ii < 4; ++ii) {
            int slot = tid + 256 * ii;
            int row  = slot >> 3;
            int c4   = slot & 7;
            float4 av = *(const float4*)(x + ((size_t)row * TT + t) * II + k0 + c4 * 4);
            unsigned short* ap = &AS[row][c4 * 4];
            ap[0] = f2bf(av.x); ap[1] = f2bf(av.y); ap[2] = f2bf(av.z); ap[3] = f2bf(av.w);
            float4 bv = *(const float4*)(Wih + (size_t)(g0 + row) * II + k0 + c4 * 4);
            unsigned short* bp = &BS[row][c4 * 4];
            bp[0] = f2bf(bv.x); bp[1] = f2bf(bv.y); bp[2] = f2bf(bv.z); bp[3] = f2bf(bv.w);
        }
        __syncthreads();

        const int kc = (lane >> 4) * 8;
        short8 a[4], b[4];
#pragma unroll
        for (int mi = 0; mi < 4; ++mi)
            a[mi] = *(const short8*)&AS[wr * 64 + mi * 16 + (lane & 15)][kc];
#pragma unroll
        for (int ni = 0; ni < 4; ++ni)
            b[ni] = *(const short8*)&BS[wc * 64 + ni * 16 + (lane & 15)][kc];
#pragma unroll
        for (int mi = 0; mi < 4; ++mi)
#pragma unroll
            for (int ni = 0; ni < 4; ++ni)
                acc[mi][ni] = __builtin_amdgcn_mfma_f32_16x16x32_bf16(a[mi], b[ni], acc[mi][ni], 0, 0, 0);
        __syncthreads();
    }

#pragma unroll
    for (int ni = 0; ni < 4; ++ni) {
        const int col = wc * 64 + ni * 16 + (lane & 15);
        const float bias = bih[g0 + col];
#pragma unroll
        for (int mi = 0; mi < 4; ++mi) {
#pragma unroll
            for (int i = 0; i < 4; ++i) {
                const int row = wr * 64 + mi * 16 + (lane >> 4) * 4 + i;
                xg[((size_t)t * BB + row) * G3 + g0 + col] = f2bf(acc[mi][ni][i] + bias);
            }
        }
    }
}

// ---------------------------------------------------------------------------
// Kernel 2 v5: v3 topology (128 blocks x 2 waves, LDS-staged A-fragments,
// W_hh in registers, tagged u64 parity exchange) with three serial-path cuts:
//  - poll = 16 x dwordx4 (tags at .y/.w) instead of 32 x 8B atomics
//  - xg prefetched one step ahead (u32 words), issued post-detect
//  - h-tile LDS double-buffered -> ONE barrier per step (stage(t+1) can't
//    race reads of t: different parity; wave skew bounded by the publish
//    induction: tag t+2 in parity p only lands after all t+1 tags observed,
//    which implies every member consumed h(t) from p).
// ---------------------------------------------------------------------------
#define NTH2 128

__global__ __launch_bounds__(NTH2, 1) void gru_scan(
    const unsigned short* __restrict__ xg,    // [T,B,1536] bf16
    const float* __restrict__ Whh,            // [1536,512]
    const float* __restrict__ bhh,            // [1536]
    float* __restrict__ out,                  // [B,H]
    unsigned long long* __restrict__ hb64)    // [2][B][256] tagged pairs
{
    __shared__ unsigned int hF[2 * 4096];     // 32 KiB, [parity][ks][1024B frag]

    const int g    = blockIdx.x & 7;     // group: batch rows 16g..16g+15
    const int m    = blockIdx.x >> 3;    // member: h dims 32m..32m+31
    const int tid  = threadIdx.x;
    const int lane = tid & 63;
    const int w    = tid >> 6;           // wave 0/1: j half-tile

    // ---- W_hh slice -> registers (B-fragment order), one-time ----
    const int jj = m * 32 + w * 16 + (lane & 15);   // this lane's global j
    short8 Wr[3][16];
    {
        const int kofs = (lane >> 4) * 8;
#pragma unroll
        for (int q = 0; q < 3; ++q) {
            const float* wrow = Whh + ((size_t)(q * HH + jj)) * HH + kofs;
#pragma unroll
            for (int ks = 0; ks < 16; ++ks) {
                float4 v0 = *(const float4*)(wrow + ks * 32);
                float4 v1 = *(const float4*)(wrow + ks * 32 + 4);
                union { short8 s; unsigned int u[4]; } pk;
                pk.u[0] = (unsigned int)f2bf(v0.x) | ((unsigned int)f2bf(v0.y) << 16);
                pk.u[1] = (unsigned int)f2bf(v0.z) | ((unsigned int)f2bf(v0.w) << 16);
                pk.u[2] = (unsigned int)f2bf(v1.x) | ((unsigned int)f2bf(v1.y) << 16);
                pk.u[3] = (unsigned int)f2bf(v1.z) | ((unsigned int)f2bf(v1.w) << 16);
                Wr[q][ks] = pk.s;
            }
        }
    }

    const float bhr = bhh[jj];
    const float bhz = bhh[HH + jj];
    const float bhn = bhh[2 * HH + jj];
    const int b0 = (lane >> 4) * 4;                 // first of 4 batch rows

    float hh[4] = {0.0f, 0.0f, 0.0f, 0.0f};        // carried fp32 state

    // ---- poll/stage mapping: thread tid owns, for every ks:
    //   row = tid&15, lg = (tid>>4)&3, e2pair = tid>>6
    //   src pairs  = ks*16 + lg*4 + e2pair*2, +1   (16B load)
    //   dst dwords = ks*256 + lg*64 + row*4 + e2pair*2, +1
    const int prow = tid & 15;
    const int plg  = (tid >> 4) & 3;
    const int pe2  = tid >> 6;
    const char* pollb = (const char*)hb64 +
        (((size_t)g * 16 + prow) * 256 + plg * 4 + pe2 * 2) * 8;
    const size_t PARITY_B = (size_t)BB * 256 * 8;
    const int dstb = plg * 64 + prow * 4 + pe2 * 2;

    // ---- xg prefetch offsets (u32 words), one step ahead ----
    const unsigned int* xg32 = (const unsigned int*)xg;
    const unsigned int xsel = (unsigned int)(jj & 1) * 16;
    unsigned int xoff[12];
#pragma unroll
    for (int i = 0; i < 4; ++i)
#pragma unroll
        for (int q = 0; q < 3; ++q)
            xoff[i * 3 + q] = (unsigned int)(((g * 16 + b0 + i) * G3 + q * HH + (jj & ~1)) >> 1);
    const unsigned int XSTEP = (unsigned int)((BB * G3) >> 1);  // u32 words per t

    unsigned int xc[12];
#pragma unroll
    for (int v = 0; v < 12; ++v) xc[v] = xg32[xoff[v]];   // t = 0

    for (int t = 0; t < TT; ++t) {
        // ---- poll own 16 fragment quads (data IS the flag) ----
        const unsigned int want = (unsigned int)t;
        const char* pb = pollb + (size_t)(t & 1) * PARITY_B;
        u32x4 P[16];
        while (true) {
            GLD16O(P[ 0], pb, "0");    GLD16O(P[ 1], pb, "128");
            GLD16O(P[ 2], pb, "256");  GLD16O(P[ 3], pb, "384");
            GLD16O(P[ 4], pb, "512");  GLD16O(P[ 5], pb, "640");
            GLD16O(P[ 6], pb, "768");  GLD16O(P[ 7], pb, "896");
            GLD16O(P[ 8], pb, "1024"); GLD16O(P[ 9], pb, "1152");
            GLD16O(P[10], pb, "1280"); GLD16O(P[11], pb, "1408");
            GLD16O(P[12], pb, "1536"); GLD16O(P[13], pb, "1664");
            GLD16O(P[14], pb, "1792"); GLD16O(P[15], pb, "1920");
            asm volatile("s_waitcnt vmcnt(0)" ::: "memory");
            __builtin_amdgcn_sched_barrier(0);
            bool ok = true;
#pragma unroll
            for (int ks = 0; ks < 16; ++ks)
                ok &= (P[ks][1] == want) & (P[ks][3] == want);
            if (ok) break;
        }

        // ---- stage to LDS A-fragment layout (parity t&1) ----
        unsigned int* hD = &hF[(t & 1) * 4096 + dstb];
#pragma unroll
        for (int ks = 0; ks < 16; ++ks) {
            unsigned long long dv = (unsigned long long)P[ks][0] |
                                    ((unsigned long long)P[ks][2] << 32);
            *(unsigned long long*)&hD[ks * 256] = dv;
        }

        // ---- xg prefetch for t+1 (hides under compute+publish+next poll) ----
        unsigned int xn[12];
        {
            const unsigned int tw = (t < TT - 1 ? (unsigned int)(t + 1) : (unsigned int)t) * XSTEP;
#pragma unroll
            for (int v = 0; v < 12; ++v) xn[v] = xg32[xoff[v] + tw];
        }

        __syncthreads();   // staging complete (both waves) before reads

        // ---- MFMA: 3 gates x K=512; A from LDS, B from registers ----
        const char* hA = (const char*)hF + (t & 1) * 16384 + lane * 16;
        f32x4 aR = (f32x4)(0.0f), aZ = (f32x4)(0.0f), aN = (f32x4)(0.0f);
#pragma unroll
        for (int ks = 0; ks < 16; ++ks) {
            short8 a = *(const short8*)(hA + ks * 1024);
            aR = __builtin_amdgcn_mfma_f32_16x16x32_bf16(a, Wr[0][ks], aR, 0, 0, 0);
            aZ = __builtin_amdgcn_mfma_f32_16x16x32_bf16(a, Wr[1][ks], aZ, 0, 0, 0);
            aN = __builtin_amdgcn_mfma_f32_16x16x32_bf16(a, Wr[2][ks], aN, 0, 0, 0);
        }

        // ---- gates in-register; tagged publish (last act of the step) ----
        const unsigned long long tag = ((unsigned long long)(t + 1)) << 32;
        unsigned long long* dst = hb64 + (size_t)((t + 1) & 1) * BB * 256;
#pragma unroll
        for (int i = 0; i < 4; ++i) {
            float xr = bf2f((unsigned short)(xc[i * 3 + 0] >> xsel));
            float xz = bf2f((unsigned short)(xc[i * 3 + 1] >> xsel));
            float xn_ = bf2f((unsigned short)(xc[i * 3 + 2] >> xsel));
            float r = sigmoidf_fast(xr + aR[i] + bhr);
            float z = sigmoidf_fast(xz + aZ[i] + bhz);
            float n = tanhf_fast(xn_ + r * (aN[i] + bhn));
            hh[i] = (1.0f - z) * n + z * hh[i];
            unsigned int u  = (unsigned int)f2bf(hh[i]);
            unsigned int pv = (unsigned int)__shfl_xor((int)u, 1);
            if ((lane & 1) == 0) {
                unsigned long long word = tag | (unsigned long long)(u | (pv << 16));
                __hip_atomic_store(&dst[(size_t)(g * 16 + b0 + i) * 256 + (jj >> 1)], word,
                                   __ATOMIC_RELAXED, __HIP_MEMORY_SCOPE_AGENT);
            }
        }

#pragma unroll
        for (int v = 0; v < 12; ++v) xc[v] = xn[v];
    }

    // ---- final state ----
#pragma unroll
    for (int i = 0; i < 4; ++i)
        out[(size_t)(g * 16 + b0 + i) * HH + jj] = hh[i];
}

// ---------------------------------------------------------------------------
extern "C" void kernel_launch(void* const* d_in, const int* in_sizes, int n_in,
                              void* d_out, int out_size, void* d_ws, size_t ws_size,
                              hipStream_t stream) {
    const float* x   = (const float*)d_in[0];
    const float* Wih = (const float*)d_in[1];
    const float* Whh = (const float*)d_in[2];
    const float* bih = (const float*)d_in[3];
    const float* bhh = (const float*)d_in[4];
    float* out = (float*)d_out;

    const size_t XG_BYTES   = (size_t)TT * BB * G3 * 2;        // 192 MiB bf16
    unsigned short* xg      = (unsigned short*)d_ws;
    unsigned long long* hb64 = (unsigned long long*)((char*)d_ws + XG_BYTES);
    const size_t HBUF_BYTES = (size_t)2 * BB * 256 * 8;        // 512 KiB tagged pairs

    // tags must start at 0 (= h(0) valid, value 0)
    hipMemsetAsync((char*)d_ws + XG_BYTES, 0, HBUF_BYTES, stream);

    dim3 g1(G3 / 128, TT);
    xgate_gemm<<<g1, 256, 0, stream>>>(x, Wih, bih, xg);

    gru_scan<<<128, NTH2, 0, stream>>>(xg, Whh, bhh, out, hb64);
}